// Round 13
// baseline (289.820 us; speedup 1.0000x reference)
//
#include <hip/hip_runtime.h>

#define N_NODES 50000
#define N_EDGES 800000
#define NBKT 391          // ceil(50000/128) buckets of 128 nodes
#define BKT 128
#define MAXREC 2560       // bucket capacity in LDS (mean 2046, +11 sigma)
#define EPB 4096          // edges per block in count/score_bucket
#define XCBLK 6250        // xcast blocks: N_NODES*128/4/256
#define CNTBLK 196        // count blocks: ceil(800000/4096)

typedef unsigned int u32;
typedef unsigned short u16;
typedef __attribute__((ext_vector_type(2))) float float2v;
typedef __attribute__((ext_vector_type(8))) short bf16x8;
typedef __attribute__((ext_vector_type(4))) float f32x4;

__device__ __forceinline__ float bf_lo(u32 v){ return __uint_as_float(v << 16); }
__device__ __forceinline__ float bf_hi(u32 v){ return __uint_as_float(v & 0xffff0000u); }
__device__ __forceinline__ u16 f2bf(float f){
    u32 u = __float_as_uint(f);
    u += 0x7fffu + ((u >> 16) & 1u);     // round-to-nearest-even
    return (u16)(u >> 16);
}

#if __has_builtin(__builtin_amdgcn_cvt_pk_f32_fp8) && __has_builtin(__builtin_amdgcn_cvt_pk_fp8_f32)
#define HW_FP8 1
#else
#define HW_FP8 0
#endif

__device__ __forceinline__ u32 enc1_e4m3(float f){
    u32 u = __float_as_uint(f);
    u32 s = (u >> 24) & 0x80u;
    u32 a = u & 0x7fffffffu;
    if (a >= 0x43e00000u) return s | 0x7eu;          // >= 448 -> sat
    if (a < 0x3c800000u){                            // < 2^-6 -> denormal (m * 2^-9)
        float af = __uint_as_float(a) * 512.f;
        u32 m = (u32)(af + 0.5f);
        return s | m;
    }
    int e = (int)(a >> 23) - 127;
    u32 mant = (a >> 20) & 7u;
    u32 rnd = (a >> 19) & 1u;
    u32 sticky = (a & 0x7ffffu) ? 1u : 0u;
    u32 code = ((u32)(e + 7) << 3) | mant;
    code += (rnd & (sticky | (mant & 1u)));
    if (code > 0x7eu) code = 0x7eu;
    return s | code;
}

template<bool HI>
__device__ __forceinline__ float2v dec2_word(u32 v){
#if HW_FP8
    return __builtin_amdgcn_cvt_pk_f32_fp8(v, HI);
#else
    u32 v16 = HI ? (v >> 16) : (v & 0xffffu);
    float2v r;
    #pragma unroll
    for (int t = 0; t < 2; t++){
        u32 b = (v16 >> (8 * t)) & 0xffu;
        u32 e = (b >> 3) & 15u, m = b & 7u;
        float fv = e ? __uint_as_float(((e + 120u) << 23) | (m << 20)) : (float)m * 0.001953125f;
        r[t] = (b & 0x80u) ? -fv : fv;
    }
    return r;
#endif
}
__device__ __forceinline__ u32 encpk_lo(float a, float b, u32 old){
#if HW_FP8
    return (u32)__builtin_amdgcn_cvt_pk_fp8_f32(a, b, (int)old, false);
#else
    return (old & 0xffff0000u) | enc1_e4m3(a) | (enc1_e4m3(b) << 8);
#endif
}
__device__ __forceinline__ u32 encpk_hi(float a, float b, u32 old){
#if HW_FP8
    return (u32)__builtin_amdgcn_cvt_pk_fp8_f32(a, b, (int)old, true);
#else
    return (old & 0x0000ffffu) | (enc1_e4m3(a) << 16) | (enc1_e4m3(b) << 24);
#endif
}

// --------- setup: xcast | weight prep | bucket count histograms (bcnt pre-zeroed)
__global__ __launch_bounds__(256) void setup_kernel(const float* __restrict__ x,
        const float* __restrict__ w_s2d, const float* __restrict__ w_d2s,
        const float* __restrict__ w_e1, const float* __restrict__ w_g1,
        const float* __restrict__ b_e1, const int* __restrict__ eidx,
        uint2* __restrict__ xb2, u32* __restrict__ xf8,
        u16* __restrict__ pk1, u16* __restrict__ pkM,
        u16* __restrict__ pkG, float* __restrict__ bias1, u32* __restrict__ bcnt){
    const int blk = blockIdx.x, tid = threadIdx.x;
    if (blk < XCBLK){
        int i = blk * 256 + tid;                 // one float4 (4 elems) per thread
        float4 v = ((const float4*)x)[i];
        uint2 o;
        o.x = (u32)f2bf(v.x) | ((u32)f2bf(v.y) << 16);
        o.y = (u32)f2bf(v.z) | ((u32)f2bf(v.w) << 16);
        xb2[i] = o;
        u32 w8 = encpk_lo(v.x, v.y, 0u);
        xf8[i] = encpk_hi(v.z, v.w, w8);
    } else if (blk < XCBLK + 386){
        int idx = (blk - XCBLK) * 256 + tid;
        if (idx < 32768){
            int j = idx & 7, g = (idx >> 3) & 3, ch = (idx >> 5) & 255, ks = idx >> 13;
            int k = ks * 32 + g * 8 + j;
            float v = (ch < 128) ? w_e1[k * 128 + ch] : w_e1[(128 + k) * 128 + (ch - 128)];
            pk1[idx] = f2bf(v);
        } else if (idx < 65536){
            int i2 = idx - 32768;
            int j = i2 & 7, g = (i2 >> 3) & 3, ch = (i2 >> 5) & 255, ks = i2 >> 13;
            int k = ks * 32 + g * 8 + j;
            float v = (ch < 128) ? w_s2d[k * 128 + ch] : w_d2s[k * 128 + (ch - 128)];
            pkM[i2] = f2bf(v);
        } else if (idx < 98304){
            int i2 = idx - 65536;
            int j = i2 & 7, g = (i2 >> 3) & 3, oc = (i2 >> 5) & 127, ks = i2 >> 12;
            int k = ks * 32 + g * 8 + j;
            pkG[i2] = f2bf(w_g1[k * 128 + oc]);
        } else if (idx < 98560){
            int o = idx - 98304;
            bias1[o] = (o < 128) ? b_e1[o] : 0.f;
        }
    } else {
        // count blocks: LDS-privatized bucket histogram (bcnt zeroed via memset)
        __shared__ u32 h[2 * NBKT];
        for (int i = tid; i < 2 * NBKT; i += 256) h[i] = 0u;
        __syncthreads();
        const int e0 = (blk - XCBLK - 386) * EPB;
        for (int i = tid; i < EPB; i += 256){
            int e = e0 + i;
            if (e < N_EDGES){
                atomicAdd(&h[eidx[N_EDGES + e] >> 7], 1u);          // dst side
                atomicAdd(&h[NBKT + (eidx[e] >> 7)], 1u);           // src side
            }
        }
        __syncthreads();
        for (int i = tid; i < 2 * NBKT; i += 256){
            u32 v = h[i];
            if (v) atomicAdd(&bcnt[i], v);
        }
    }
}

// ----------------------- score projections T1 = [A|B] fp8, via MFMA
__global__ __launch_bounds__(256) void proj_mfma_kernel(const u16* __restrict__ xb16,
        const u16* __restrict__ pk1, const float* __restrict__ bias1, u32* __restrict__ T1){
    const int tid = threadIdx.x;
    const int w = tid >> 6, l = tid & 63;
    const int l16 = l & 15, lg = l >> 4;
    const int n0 = blockIdx.x * 16;
    const int node = n0 + l16;
    bf16x8 bx[4];
    #pragma unroll
    for (int ks = 0; ks < 4; ks++)
        bx[ks] = *(const bf16x8*)(xb16 + node * 128 + ks * 32 + lg * 8);
    #pragma unroll
    for (int ct = 0; ct < 4; ct++){
        const int ch0 = w * 64 + ct * 16;
        f32x4 acc = {0.f, 0.f, 0.f, 0.f};
        #pragma unroll
        for (int ks = 0; ks < 4; ks++){
            bf16x8 a = *(const bf16x8*)(pk1 + ((ks * 256 + ch0 + l16) * 4 + lg) * 8);
            acc = __builtin_amdgcn_mfma_f32_16x16x32_bf16(a, bx[ks], acc, 0, 0, 0);
        }
        const int chb = ch0 + lg * 4;
        float f0 = acc[0] + bias1[chb],     f1 = acc[1] + bias1[chb + 1];
        float f2 = acc[2] + bias1[chb + 2], f3 = acc[3] + bias1[chb + 3];
        u32 wd = encpk_lo(f0, f1, 0u);
        wd = encpk_hi(f2, f3, wd);
        T1[node * 64 + (chb >> 2)] = wd;
    }
}

// -------------------------------------------------- bucket exclusive scan x2
__global__ __launch_bounds__(512) void bucket_scan_kernel(const u32* __restrict__ bcnt,
        u32* __restrict__ bbase, u32* __restrict__ bnext){
    __shared__ u32 sa[512], sb[512];
    const int t = threadIdx.x;
    const u32* c = bcnt + blockIdx.x * NBKT;
    u32* base = bbase + blockIdx.x * (NBKT + 1);
    u32* nxt  = bnext + blockIdx.x * NBKT;
    sa[t] = (t < NBKT) ? c[t] : 0u;
    __syncthreads();
    u32 *a = sa, *b = sb;
    for (int off = 1; off < 512; off <<= 1){
        u32 v = a[t]; if (t >= off) v += a[t - off];
        b[t] = v; __syncthreads();
        u32* tmp = a; a = b; b = tmp;
    }
    if (t < NBKT){
        u32 ex = t ? a[t - 1] : 0u;
        base[t] = ex; nxt[t] = ex;
        if (t == NBKT - 1) base[NBKT] = a[t];
    }
}

// ----- scores (8 lanes/edge, fp8 T1) + bucket append, fused per 4096-edge block
__global__ __launch_bounds__(256) void score_bucket_kernel(const u32* __restrict__ T1w,
        const int* __restrict__ eidx, const float* __restrict__ w_e2, const float* __restrict__ b_e2,
        u32* __restrict__ bnext, uint2* __restrict__ Bd, uint2* __restrict__ Bs){
    __shared__ u16 ssc[EPB];                // 8 KB scores
    __shared__ u32 hd[NBKT], hs[NBKT];      // per-block counts
    __shared__ u32 rbd[NBKT], rbs[NBKT];    // reserved global bases
    __shared__ u32 ld[NBKT], ls[NBKT];      // local ranks
    const int tid = threadIdx.x;
    const int e0 = blockIdx.x * EPB;
    // ---- phase A: edge scores into LDS
    {
        const float be2 = b_e2[0];
        const int l8 = tid & 7, esl = tid >> 3;       // 32 edges per pass
        const float2v* wvp = (const float2v*)(w_e2 + l8 * 16);
        const float2v w0 = wvp[0], w1 = wvp[1], w2 = wvp[2], w3 = wvp[3];
        const float2v w4 = wvp[4], w5 = wvp[5], w6 = wvp[6], w7 = wvp[7];
        const float2v zero = {0.f, 0.f};
        for (int pass = 0; pass < EPB / 32; pass++){
            const int e = e0 + pass * 32 + esl;
            float p = 0.f;
            if (e < N_EDGES){
                const int src = eidx[e];
                const int dst = eidx[N_EDGES + e];
                const uint4 a8 = *(const uint4*)(T1w + src * 64 + l8 * 4);
                const uint4 b8 = *(const uint4*)(T1w + dst * 64 + 32 + l8 * 4);
                float2v acc = {0.f, 0.f};
                float2v t;
                t = __builtin_elementwise_max(dec2_word<false>(a8.x) + dec2_word<false>(b8.x), zero); acc += t * w0;
                t = __builtin_elementwise_max(dec2_word<true >(a8.x) + dec2_word<true >(b8.x), zero); acc += t * w1;
                t = __builtin_elementwise_max(dec2_word<false>(a8.y) + dec2_word<false>(b8.y), zero); acc += t * w2;
                t = __builtin_elementwise_max(dec2_word<true >(a8.y) + dec2_word<true >(b8.y), zero); acc += t * w3;
                t = __builtin_elementwise_max(dec2_word<false>(a8.z) + dec2_word<false>(b8.z), zero); acc += t * w4;
                t = __builtin_elementwise_max(dec2_word<true >(a8.z) + dec2_word<true >(b8.z), zero); acc += t * w5;
                t = __builtin_elementwise_max(dec2_word<false>(a8.w) + dec2_word<false>(b8.w), zero); acc += t * w6;
                t = __builtin_elementwise_max(dec2_word<true >(a8.w) + dec2_word<true >(b8.w), zero); acc += t * w7;
                p = acc[0] + acc[1];
            }
            p += __shfl_xor(p, 1, 64);
            p += __shfl_xor(p, 2, 64);
            p += __shfl_xor(p, 4, 64);
            if (l8 == 0 && e < N_EDGES){
                float sc = 1.f / (1.f + __expf(-(p + be2)));
                ssc[pass * 32 + esl] = f2bf(sc);
            }
        }
    }
    // ---- phase B: bucket append with LDS scores
    for (int i = tid; i < NBKT; i += 256){ hd[i] = 0u; hs[i] = 0u; ld[i] = 0u; ls[i] = 0u; }
    __syncthreads();
    for (int i = tid; i < EPB; i += 256){
        int e = e0 + i;
        if (e < N_EDGES){
            atomicAdd(&hd[eidx[N_EDGES + e] >> 7], 1u);
            atomicAdd(&hs[eidx[e] >> 7], 1u);
        }
    }
    __syncthreads();
    for (int i = tid; i < NBKT; i += 256){
        rbd[i] = hd[i] ? atomicAdd(&bnext[i], hd[i]) : 0u;
        rbs[i] = hs[i] ? atomicAdd(&bnext[NBKT + i], hs[i]) : 0u;
    }
    __syncthreads();
    for (int i = tid; i < EPB; i += 256){
        int e = e0 + i;
        if (e < N_EDGES){
            int src = eidx[e], dst = eidx[N_EDGES + e];
            u32 sc = (u32)ssc[i] << 16;
            int bd = dst >> 7;
            u32 r = atomicAdd(&ld[bd], 1u);
            Bd[rbd[bd] + r] = make_uint2(sc | (u32)src, (u32)(dst & 127));
            int bs_ = src >> 7;
            u32 r2 = atomicAdd(&ls[bs_], 1u);
            Bs[rbs[bs_] + r2] = make_uint2(sc | (u32)dst, (u32)(src & 127));
        }
    }
}

// -------------------- phase 2: per-bucket local CSR build (no global atomics)
__global__ __launch_bounds__(256) void bucket2_kernel(const uint2* __restrict__ Bd, const uint2* __restrict__ Bs,
        const u32* __restrict__ bbase,
        u32* __restrict__ cnt_dst, u32* __restrict__ start_dst,
        u32* __restrict__ cnt_src, u32* __restrict__ start_src,
        u32* __restrict__ in_pay, u32* __restrict__ out_pay){
    __shared__ u32 pays[MAXREC];
    __shared__ u16 locs[MAXREC];
    __shared__ u32 hist[BKT], nxt[BKT], pref[BKT];
    const int tid = threadIdx.x;
    const int side = blockIdx.x >= NBKT ? 1 : 0;
    const int b = side ? blockIdx.x - NBKT : blockIdx.x;
    const uint2* __restrict__ B = side ? Bs : Bd;
    const u32* bb = bbase + side * (NBKT + 1);
    const u32 base = bb[b];
    const u32 nrec = bb[b + 1] - base;
    u32* cnto = side ? cnt_src : cnt_dst;
    u32* sto  = side ? start_src : start_dst;
    u32* payo = side ? out_pay : in_pay;
    for (int i = tid; i < BKT; i += 256) hist[i] = 0u;
    __syncthreads();
    for (u32 i = tid; i < nrec; i += 256){
        uint2 r = B[base + i];
        if (i < MAXREC){ pays[i] = r.x; locs[i] = (u16)r.y; }
        atomicAdd(&hist[r.y & (BKT - 1)], 1u);
    }
    __syncthreads();
    if (tid < BKT) pref[tid] = hist[tid];
    __syncthreads();
    for (int off = 1; off < BKT; off <<= 1){
        u32 v = 0;
        if (tid < BKT){ v = pref[tid]; if (tid >= off) v += pref[tid - off]; }
        __syncthreads();
        if (tid < BKT) pref[tid] = v;
        __syncthreads();
    }
    if (tid < BKT){
        u32 ex = tid ? pref[tid - 1] : 0u;
        u32 gstart = base + ex;
        nxt[tid] = gstart;
        int node = b * BKT + tid;
        if (node < N_NODES){ cnto[node] = hist[tid]; sto[node] = gstart; }
    }
    __syncthreads();
    for (u32 i = tid; i < nrec; i += 256){
        u32 pay; int loc;
        if (i < MAXREC){ pay = pays[i]; loc = locs[i]; }
        else { uint2 r = B[base + i]; pay = r.x; loc = (int)(r.y & (BKT - 1)); }
        u32 pos = atomicAdd(&nxt[loc], 1u);
        payo[pos] = pay;
    }
}

// ------------------- gather weighted raw-x sums (fp8 table, 8-deep ILP)
__global__ __launch_bounds__(256) void gather_kernel(const u32* __restrict__ xf8,
        const u32* __restrict__ in_pay, const u32* __restrict__ out_pay,
        const u32* __restrict__ cnt_dst, const u32* __restrict__ start_dst,
        const u32* __restrict__ cnt_src, const u32* __restrict__ start_src,
        u32* __restrict__ Y, float* __restrict__ ssin, float* __restrict__ ssout){
    const int w = threadIdx.x >> 6, lane = threadIdx.x & 63;
    const int node = blockIdx.x * 2 + (w >> 1);
    const int dir = w & 1;
    const u32* __restrict__ pay = dir ? out_pay : in_pay;
    const u32 deg = dir ? cnt_src[node] : cnt_dst[node];
    const u32 st  = dir ? start_src[node] : start_dst[node];
    const int half = lane >> 5, l5 = lane & 31;
    float2v AL = {0.f, 0.f}, AH = {0.f, 0.f};
    float ss = 0.f;
    u32 j = (u32)half;
    for (; j + 14 < deg; j += 16){
        u32 p0 = pay[st+j],    p1 = pay[st+j+2],  p2 = pay[st+j+4],  p3 = pay[st+j+6];
        u32 p4 = pay[st+j+8],  p5 = pay[st+j+10], p6 = pay[st+j+12], p7 = pay[st+j+14];
        u32 v0 = xf8[(p0 & 0xffffu)*32 + l5], v1 = xf8[(p1 & 0xffffu)*32 + l5];
        u32 v2 = xf8[(p2 & 0xffffu)*32 + l5], v3 = xf8[(p3 & 0xffffu)*32 + l5];
        u32 v4 = xf8[(p4 & 0xffffu)*32 + l5], v5 = xf8[(p5 & 0xffffu)*32 + l5];
        u32 v6 = xf8[(p6 & 0xffffu)*32 + l5], v7 = xf8[(p7 & 0xffffu)*32 + l5];
        float s0 = __uint_as_float(p0 & 0xffff0000u), s1 = __uint_as_float(p1 & 0xffff0000u);
        float s2 = __uint_as_float(p2 & 0xffff0000u), s3 = __uint_as_float(p3 & 0xffff0000u);
        float s4 = __uint_as_float(p4 & 0xffff0000u), s5 = __uint_as_float(p5 & 0xffff0000u);
        float s6 = __uint_as_float(p6 & 0xffff0000u), s7 = __uint_as_float(p7 & 0xffff0000u);
        AL += dec2_word<false>(v0) * s0;  AH += dec2_word<true>(v0) * s0;
        AL += dec2_word<false>(v1) * s1;  AH += dec2_word<true>(v1) * s1;
        AL += dec2_word<false>(v2) * s2;  AH += dec2_word<true>(v2) * s2;
        AL += dec2_word<false>(v3) * s3;  AH += dec2_word<true>(v3) * s3;
        AL += dec2_word<false>(v4) * s4;  AH += dec2_word<true>(v4) * s4;
        AL += dec2_word<false>(v5) * s5;  AH += dec2_word<true>(v5) * s5;
        AL += dec2_word<false>(v6) * s6;  AH += dec2_word<true>(v6) * s6;
        AL += dec2_word<false>(v7) * s7;  AH += dec2_word<true>(v7) * s7;
        ss += s0 + s1 + s2 + s3 + s4 + s5 + s6 + s7;
    }
    for (; j + 6 < deg; j += 8){
        u32 p0 = pay[st+j], p1 = pay[st+j+2], p2 = pay[st+j+4], p3 = pay[st+j+6];
        u32 v0 = xf8[(p0 & 0xffffu)*32 + l5], v1 = xf8[(p1 & 0xffffu)*32 + l5];
        u32 v2 = xf8[(p2 & 0xffffu)*32 + l5], v3 = xf8[(p3 & 0xffffu)*32 + l5];
        float s0 = __uint_as_float(p0 & 0xffff0000u), s1 = __uint_as_float(p1 & 0xffff0000u);
        float s2 = __uint_as_float(p2 & 0xffff0000u), s3 = __uint_as_float(p3 & 0xffff0000u);
        AL += dec2_word<false>(v0) * s0;  AH += dec2_word<true>(v0) * s0;
        AL += dec2_word<false>(v1) * s1;  AH += dec2_word<true>(v1) * s1;
        AL += dec2_word<false>(v2) * s2;  AH += dec2_word<true>(v2) * s2;
        AL += dec2_word<false>(v3) * s3;  AH += dec2_word<true>(v3) * s3;
        ss += s0 + s1 + s2 + s3;
    }
    for (; j < deg; j += 2){
        u32 pl = pay[st + j];
        u32 v = xf8[(pl & 0xffffu)*32 + l5];
        float sc = __uint_as_float(pl & 0xffff0000u);
        AL += dec2_word<false>(v) * sc;
        AH += dec2_word<true>(v) * sc;
        ss += sc;
    }
    float a0 = AL[0], a1 = AL[1], a2 = AH[0], a3 = AH[1];
    a0 += __shfl_xor(a0, 32, 64);
    a1 += __shfl_xor(a1, 32, 64);
    a2 += __shfl_xor(a2, 32, 64);
    a3 += __shfl_xor(a3, 32, 64);
    ss += __shfl_xor(ss, 32, 64);
    if (half == 0){
        uint2 o;
        o.x = (u32)f2bf(a0) | ((u32)f2bf(a1) << 16);
        o.y = (u32)f2bf(a2) | ((u32)f2bf(a3) << 16);
        *(uint2*)(Y + node * 128 + dir * 64 + l5 * 2) = o;
    }
    if (lane == 0){
        if (dir) ssout[node] = ss; else ssin[node] = ss;
    }
}

// ------------- finale: msg GEMMs + normalize + gate MLP + fuse + residual
__global__ __launch_bounds__(256) void finale_mfma_kernel(const u32* __restrict__ Yw,
        const float* __restrict__ x,
        const u16* __restrict__ pkM, const u16* __restrict__ pkG,
        const float* __restrict__ b_s2d, const float* __restrict__ b_d2s,
        const float* __restrict__ ssin, const float* __restrict__ ssout,
        const u32* __restrict__ cnt_dst, const u32* __restrict__ cnt_src,
        const float* __restrict__ b_g1, const float* __restrict__ w_g2, const float* __restrict__ b_g2,
        float* __restrict__ out){
    __shared__ u32 Hsh[16][132];
    __shared__ float part[16][17];
    __shared__ float gl[16];
    const int tid = threadIdx.x;
    const int w = tid >> 6, l = tid & 63;
    const int l16 = l & 15, lg = l >> 4;
    const int n0 = blockIdx.x * 16;
    const int node = n0 + l16;
    const int dir = w >> 1;
    const int cb = (w & 1) * 64;
    const u16* Yh = (const u16*)Yw;
    bf16x8 yf[4];
    #pragma unroll
    for (int ks = 0; ks < 4; ks++)
        yf[ks] = *(const bf16x8*)(Yh + node * 256 + dir * 128 + ks * 32 + lg * 8);
    const float ssv  = dir ? ssout[node] : ssin[node];
    const float dinv = 1.f / fmaxf((float)(dir ? cnt_src[node] : cnt_dst[node]), 1.f);
    const float* bv = dir ? b_d2s : b_s2d;
    #pragma unroll
    for (int ct = 0; ct < 4; ct++){
        const int chl = cb + ct * 16;
        f32x4 acc = {0.f, 0.f, 0.f, 0.f};
        #pragma unroll
        for (int ks = 0; ks < 4; ks++){
            bf16x8 a = *(const bf16x8*)(pkM + ((ks * 256 + dir * 128 + chl + l16) * 4 + lg) * 8);
            acc = __builtin_amdgcn_mfma_f32_16x16x32_bf16(a, yf[ks], acc, 0, 0, 0);
        }
        const int chb = chl + lg * 4;
        float h0 = (acc[0] + ssv * bv[chb])     * dinv;
        float h1 = (acc[1] + ssv * bv[chb + 1]) * dinv;
        float h2 = (acc[2] + ssv * bv[chb + 2]) * dinv;
        float h3 = (acc[3] + ssv * bv[chb + 3]) * dinv;
        const int wi = (dir * 128 + chb) >> 1;
        Hsh[l16][wi]     = (u32)f2bf(h0) | ((u32)f2bf(h1) << 16);
        Hsh[l16][wi + 1] = (u32)f2bf(h2) | ((u32)f2bf(h3) << 16);
    }
    __syncthreads();
    bf16x8 hb[8];
    #pragma unroll
    for (int ks = 0; ks < 8; ks++)
        hb[ks] = *(const bf16x8*)((const u16*)&Hsh[l16][0] + ks * 32 + lg * 8);
    float p = 0.f;
    #pragma unroll
    for (int ct2 = 0; ct2 < 2; ct2++){
        const int oc0 = w * 32 + ct2 * 16;
        f32x4 acc = {0.f, 0.f, 0.f, 0.f};
        #pragma unroll
        for (int ks = 0; ks < 8; ks++){
            bf16x8 a = *(const bf16x8*)(pkG + ((ks * 128 + oc0 + l16) * 4 + lg) * 8);
            acc = __builtin_amdgcn_mfma_f32_16x16x32_bf16(a, hb[ks], acc, 0, 0, 0);
        }
        const int ob = oc0 + lg * 4;
        #pragma unroll
        for (int r = 0; r < 4; r++)
            p += fmaxf(acc[r] + b_g1[ob + r], 0.f) * w_g2[ob + r];
    }
    part[l16][w * 4 + lg] = p;
    __syncthreads();
    if (tid < 16){
        float s = 0.f;
        #pragma unroll
        for (int i = 0; i < 16; i++) s += part[tid][i];
        gl[tid] = 1.f / (1.f + __expf(-(s + b_g2[0])));
    }
    __syncthreads();
    {
        const int nn = tid >> 4, o = (tid & 15) * 8;
        const float gv = gl[nn];
        const int gbase = (n0 + nn) * 128 + o;
        float4 x0 = *(const float4*)(x + gbase);
        float4 x1 = *(const float4*)(x + gbase + 4);
        float r[8];
        #pragma unroll
        for (int t = 0; t < 4; t++){
            u32 hi = Hsh[nn][(o >> 1) + t];
            u32 ho = Hsh[nn][64 + (o >> 1) + t];
            r[2*t]   = gv * bf_lo(hi) + (1.f - gv) * bf_lo(ho);
            r[2*t+1] = gv * bf_hi(hi) + (1.f - gv) * bf_hi(ho);
        }
        *(float4*)(out + gbase)     = make_float4(r[0]+x0.x, r[1]+x0.y, r[2]+x0.z, r[3]+x0.w);
        *(float4*)(out + gbase + 4) = make_float4(r[4]+x1.x, r[5]+x1.y, r[6]+x1.z, r[7]+x1.w);
    }
}

extern "C" void kernel_launch(void* const* d_in, const int* in_sizes, int n_in,
                              void* d_out, int out_size, void* d_ws, size_t ws_size,
                              hipStream_t stream){
    const float* x     = (const float*)d_in[0];
    const int*   ei    = (const int*)d_in[1];          // int32 (JAX x64 off)
    const float* w_s2d = (const float*)d_in[2];
    const float* b_s2d = (const float*)d_in[3];
    const float* w_d2s = (const float*)d_in[4];
    const float* b_d2s = (const float*)d_in[5];
    const float* w_e1  = (const float*)d_in[6];
    const float* b_e1  = (const float*)d_in[7];
    const float* w_e2  = (const float*)d_in[8];
    const float* b_e2  = (const float*)d_in[9];
    const float* w_g1  = (const float*)d_in[10];
    const float* b_g1  = (const float*)d_in[11];
    const float* w_g2  = (const float*)d_in[12];
    const float* b_g2  = (const float*)d_in[13];
    float* out = (float*)d_out;
    u32*   T1  = (u32*)d_out;                    // fp8 [A|B], first 12.8 MB
    uint2* Bd  = (uint2*)((u32*)d_out + 3200000); // second half: 6.4 MB
    uint2* Bs  = Bd + N_EDGES;                    // + 6.4 MB (= 25.6 MB total)
    u32*   Y   = (u32*)d_out;                    // bf16 [y_in|y_out] (after bucket2)

    char* ws = (char*)d_ws;
    size_t off = 0;
    #define TAKE(name, bytes) char* name = ws + off; off += (((size_t)(bytes)) + 511) & ~(size_t)511;
    TAKE(pk1_b,   32768 * 2)
    TAKE(pkM_b,   32768 * 2)
    TAKE(pkG_b,   32768 * 2)
    TAKE(bias1_b, 256 * 4)
    TAKE(xb_b,    (size_t)N_NODES * 128 * 2)  // x in bf16 (proj), 12.8 MB
    TAKE(xf8_b,   (size_t)N_NODES * 128)      // x in fp8 (gather), 6.4 MB
    TAKE(bcnt_b,  (size_t)2 * NBKT * 4)
    TAKE(bbase_b, (size_t)2 * (NBKT + 1) * 4)
    TAKE(bnext_b, (size_t)2 * NBKT * 4)
    TAKE(cnt_b,   (size_t)2 * N_NODES * 4)    // cnt_dst | cnt_src
    TAKE(sd_b,    (size_t)N_NODES * 4)        // start_dst
    TAKE(ss2_b,   (size_t)N_NODES * 4)        // start_src
    TAKE(ipay_b,  (size_t)N_EDGES * 4)
    TAKE(opay_b,  (size_t)N_EDGES * 4)
    TAKE(ssin_b,  (size_t)N_NODES * 4)
    TAKE(ssout_b, (size_t)N_NODES * 4)
    #undef TAKE
    (void)ws_size; (void)in_sizes; (void)n_in; (void)out_size;
    // total ~28 MB

    hipMemsetAsync(bcnt_b, 0, (size_t)2 * NBKT * 4, stream);
    setup_kernel<<<XCBLK + 386 + CNTBLK, 256, 0, stream>>>(x, w_s2d, w_d2s, w_e1, w_g1, b_e1, ei,
        (uint2*)xb_b, (u32*)xf8_b, (u16*)pk1_b, (u16*)pkM_b, (u16*)pkG_b,
        (float*)bias1_b, (u32*)bcnt_b);
    proj_mfma_kernel<<<N_NODES / 16, 256, 0, stream>>>((const u16*)xb_b,
        (const u16*)pk1_b, (const float*)bias1_b, T1);
    bucket_scan_kernel<<<2, 512, 0, stream>>>((const u32*)bcnt_b, (u32*)bbase_b, (u32*)bnext_b);
    score_bucket_kernel<<<(N_EDGES + EPB - 1) / EPB, 256, 0, stream>>>((const u32*)T1, ei, w_e2, b_e2,
        (u32*)bnext_b, Bd, Bs);
    bucket2_kernel<<<2 * NBKT, 256, 0, stream>>>(Bd, Bs, (const u32*)bbase_b,
        (u32*)cnt_b, (u32*)sd_b, (u32*)cnt_b + N_NODES, (u32*)ss2_b,
        (u32*)ipay_b, (u32*)opay_b);
    gather_kernel<<<N_NODES / 2, 256, 0, stream>>>((const u32*)xf8_b,
        (const u32*)ipay_b, (const u32*)opay_b,
        (const u32*)cnt_b, (const u32*)sd_b, (const u32*)cnt_b + N_NODES, (const u32*)ss2_b,
        Y, (float*)ssin_b, (float*)ssout_b);
    finale_mfma_kernel<<<N_NODES / 16, 256, 0, stream>>>((const u32*)Y, x,
        (const u16*)pkM_b, (const u16*)pkG_b, b_s2d, b_d2s,
        (const float*)ssin_b, (const float*)ssout_b,
        (const u32*)cnt_b, (const u32*)cnt_b + N_NODES,
        b_g1, w_g2, b_g2, out);
}

// Round 14
// 225.121 us; speedup vs baseline: 1.2874x; 1.2874x over previous
//
#include <hip/hip_runtime.h>

#define N_NODES 50000
#define N_EDGES 800000
#define NBKT 391          // ceil(50000/128) buckets of 128 nodes
#define BKT 128
#define MAXREC 2560       // bucket capacity in LDS (mean 2046, +11 sigma)
#define EPB 4096          // edges per block in count/bucket1
#define XCBLK 6250        // xcast blocks: N_NODES*128/4/256
#define CNTBLK 196        // count blocks: ceil(800000/4096)

typedef unsigned int u32;
typedef unsigned short u16;
typedef __attribute__((ext_vector_type(2))) float float2v;
typedef __attribute__((ext_vector_type(8))) short bf16x8;
typedef __attribute__((ext_vector_type(4))) float f32x4;

__device__ __forceinline__ float bf_lo(u32 v){ return __uint_as_float(v << 16); }
__device__ __forceinline__ float bf_hi(u32 v){ return __uint_as_float(v & 0xffff0000u); }
__device__ __forceinline__ u16 f2bf(float f){
    u32 u = __float_as_uint(f);
    u += 0x7fffu + ((u >> 16) & 1u);     // round-to-nearest-even
    return (u16)(u >> 16);
}

#if __has_builtin(__builtin_amdgcn_cvt_pk_f32_fp8) && __has_builtin(__builtin_amdgcn_cvt_pk_fp8_f32)
#define HW_FP8 1
#else
#define HW_FP8 0
#endif

__device__ __forceinline__ u32 enc1_e4m3(float f){
    u32 u = __float_as_uint(f);
    u32 s = (u >> 24) & 0x80u;
    u32 a = u & 0x7fffffffu;
    if (a >= 0x43e00000u) return s | 0x7eu;          // >= 448 -> sat
    if (a < 0x3c800000u){                            // < 2^-6 -> denormal (m * 2^-9)
        float af = __uint_as_float(a) * 512.f;
        u32 m = (u32)(af + 0.5f);
        return s | m;
    }
    int e = (int)(a >> 23) - 127;
    u32 mant = (a >> 20) & 7u;
    u32 rnd = (a >> 19) & 1u;
    u32 sticky = (a & 0x7ffffu) ? 1u : 0u;
    u32 code = ((u32)(e + 7) << 3) | mant;
    code += (rnd & (sticky | (mant & 1u)));
    if (code > 0x7eu) code = 0x7eu;
    return s | code;
}

template<bool HI>
__device__ __forceinline__ float2v dec2_word(u32 v){
#if HW_FP8
    return __builtin_amdgcn_cvt_pk_f32_fp8(v, HI);
#else
    u32 v16 = HI ? (v >> 16) : (v & 0xffffu);
    float2v r;
    #pragma unroll
    for (int t = 0; t < 2; t++){
        u32 b = (v16 >> (8 * t)) & 0xffu;
        u32 e = (b >> 3) & 15u, m = b & 7u;
        float fv = e ? __uint_as_float(((e + 120u) << 23) | (m << 20)) : (float)m * 0.001953125f;
        r[t] = (b & 0x80u) ? -fv : fv;
    }
    return r;
#endif
}
__device__ __forceinline__ u32 encpk_lo(float a, float b, u32 old){
#if HW_FP8
    return (u32)__builtin_amdgcn_cvt_pk_fp8_f32(a, b, (int)old, false);
#else
    return (old & 0xffff0000u) | enc1_e4m3(a) | (enc1_e4m3(b) << 8);
#endif
}
__device__ __forceinline__ u32 encpk_hi(float a, float b, u32 old){
#if HW_FP8
    return (u32)__builtin_amdgcn_cvt_pk_fp8_f32(a, b, (int)old, true);
#else
    return (old & 0x0000ffffu) | (enc1_e4m3(a) << 16) | (enc1_e4m3(b) << 24);
#endif
}

// --------- setup: xcast | weight prep | bucket count histograms (bcnt pre-zeroed)
__global__ __launch_bounds__(256) void setup_kernel(const float* __restrict__ x,
        const float* __restrict__ w_s2d, const float* __restrict__ w_d2s,
        const float* __restrict__ w_e1, const float* __restrict__ w_g1,
        const float* __restrict__ b_e1, const int* __restrict__ eidx,
        uint2* __restrict__ xb2, u32* __restrict__ xf8,
        u16* __restrict__ pk1, u16* __restrict__ pkM,
        u16* __restrict__ pkG, float* __restrict__ bias1, u32* __restrict__ bcnt){
    const int blk = blockIdx.x, tid = threadIdx.x;
    if (blk < XCBLK){
        int i = blk * 256 + tid;                 // one float4 (4 elems) per thread
        float4 v = ((const float4*)x)[i];
        uint2 o;
        o.x = (u32)f2bf(v.x) | ((u32)f2bf(v.y) << 16);
        o.y = (u32)f2bf(v.z) | ((u32)f2bf(v.w) << 16);
        xb2[i] = o;
        u32 w8 = encpk_lo(v.x, v.y, 0u);
        xf8[i] = encpk_hi(v.z, v.w, w8);
    } else if (blk < XCBLK + 386){
        int idx = (blk - XCBLK) * 256 + tid;
        if (idx < 32768){
            int j = idx & 7, g = (idx >> 3) & 3, ch = (idx >> 5) & 255, ks = idx >> 13;
            int k = ks * 32 + g * 8 + j;
            float v = (ch < 128) ? w_e1[k * 128 + ch] : w_e1[(128 + k) * 128 + (ch - 128)];
            pk1[idx] = f2bf(v);
        } else if (idx < 65536){
            int i2 = idx - 32768;
            int j = i2 & 7, g = (i2 >> 3) & 3, ch = (i2 >> 5) & 255, ks = i2 >> 13;
            int k = ks * 32 + g * 8 + j;
            float v = (ch < 128) ? w_s2d[k * 128 + ch] : w_d2s[k * 128 + (ch - 128)];
            pkM[i2] = f2bf(v);
        } else if (idx < 98304){
            int i2 = idx - 65536;
            int j = i2 & 7, g = (i2 >> 3) & 3, oc = (i2 >> 5) & 127, ks = i2 >> 12;
            int k = ks * 32 + g * 8 + j;
            pkG[i2] = f2bf(w_g1[k * 128 + oc]);
        } else if (idx < 98560){
            int o = idx - 98304;
            bias1[o] = (o < 128) ? b_e1[o] : 0.f;
        }
    } else {
        // count blocks: LDS-privatized bucket histogram (bcnt zeroed via memset)
        __shared__ u32 h[2 * NBKT];
        for (int i = tid; i < 2 * NBKT; i += 256) h[i] = 0u;
        __syncthreads();
        const int e0 = (blk - XCBLK - 386) * EPB;
        for (int i = tid; i < EPB; i += 256){
            int e = e0 + i;
            if (e < N_EDGES){
                atomicAdd(&h[eidx[N_EDGES + e] >> 7], 1u);          // dst side
                atomicAdd(&h[NBKT + (eidx[e] >> 7)], 1u);           // src side
            }
        }
        __syncthreads();
        for (int i = tid; i < 2 * NBKT; i += 256){
            u32 v = h[i];
            if (v) atomicAdd(&bcnt[i], v);
        }
    }
}

// ----------------------- score projections T1 = [A|B] fp8, via MFMA
__global__ __launch_bounds__(256) void proj_mfma_kernel(const u16* __restrict__ xb16,
        const u16* __restrict__ pk1, const float* __restrict__ bias1, u32* __restrict__ T1){
    const int tid = threadIdx.x;
    const int w = tid >> 6, l = tid & 63;
    const int l16 = l & 15, lg = l >> 4;
    const int n0 = blockIdx.x * 16;
    const int node = n0 + l16;
    bf16x8 bx[4];
    #pragma unroll
    for (int ks = 0; ks < 4; ks++)
        bx[ks] = *(const bf16x8*)(xb16 + node * 128 + ks * 32 + lg * 8);
    #pragma unroll
    for (int ct = 0; ct < 4; ct++){
        const int ch0 = w * 64 + ct * 16;
        f32x4 acc = {0.f, 0.f, 0.f, 0.f};
        #pragma unroll
        for (int ks = 0; ks < 4; ks++){
            bf16x8 a = *(const bf16x8*)(pk1 + ((ks * 256 + ch0 + l16) * 4 + lg) * 8);
            acc = __builtin_amdgcn_mfma_f32_16x16x32_bf16(a, bx[ks], acc, 0, 0, 0);
        }
        const int chb = ch0 + lg * 4;
        float f0 = acc[0] + bias1[chb],     f1 = acc[1] + bias1[chb + 1];
        float f2 = acc[2] + bias1[chb + 2], f3 = acc[3] + bias1[chb + 3];
        u32 wd = encpk_lo(f0, f1, 0u);
        wd = encpk_hi(f2, f3, wd);
        T1[node * 64 + (chb >> 2)] = wd;
    }
}

// ---------------------------------------------- edge scores (no atomics)
__global__ __launch_bounds__(256) void edge_score_kernel(const u32* __restrict__ T1w, const int* __restrict__ eidx,
        const float* __restrict__ w_e2, const float* __restrict__ b_e2,
        u16* __restrict__ score){
    const int l16 = threadIdx.x & 15;
    const int e = blockIdx.x * 16 + (threadIdx.x >> 4);
    const int src = eidx[e];
    const int dst = eidx[N_EDGES + e];
    const uint2 a8 = *(const uint2*)(T1w + src * 64 + l16 * 2);
    const uint2 b8 = *(const uint2*)(T1w + dst * 64 + 32 + l16 * 2);
    const float2v* wv = (const float2v*)(w_e2 + l16 * 8);
    const float2v zero = {0.f, 0.f};
    float2v acc = {0.f, 0.f};
    {
        float2v t0 = dec2_word<false>(a8.x) + dec2_word<false>(b8.x);
        float2v t1 = dec2_word<true>(a8.x)  + dec2_word<true>(b8.x);
        float2v t2 = dec2_word<false>(a8.y) + dec2_word<false>(b8.y);
        float2v t3 = dec2_word<true>(a8.y)  + dec2_word<true>(b8.y);
        t0 = __builtin_elementwise_max(t0, zero);
        t1 = __builtin_elementwise_max(t1, zero);
        t2 = __builtin_elementwise_max(t2, zero);
        t3 = __builtin_elementwise_max(t3, zero);
        acc += t0 * wv[0];
        acc += t1 * wv[1];
        acc += t2 * wv[2];
        acc += t3 * wv[3];
    }
    float p = acc[0] + acc[1];
    p += __shfl_xor(p, 1, 64);
    p += __shfl_xor(p, 2, 64);
    p += __shfl_xor(p, 4, 64);
    p += __shfl_xor(p, 8, 64);
    if (l16 == 0){
        float sc = 1.f / (1.f + __expf(-(p + b_e2[0])));
        score[e] = f2bf(sc);
    }
}

// -------------------------------------------------- bucket exclusive scan x2
__global__ __launch_bounds__(512) void bucket_scan_kernel(const u32* __restrict__ bcnt,
        u32* __restrict__ bbase, u32* __restrict__ bnext){
    __shared__ u32 sa[512], sb[512];
    const int t = threadIdx.x;
    const u32* c = bcnt + blockIdx.x * NBKT;
    u32* base = bbase + blockIdx.x * (NBKT + 1);
    u32* nxt  = bnext + blockIdx.x * NBKT;
    sa[t] = (t < NBKT) ? c[t] : 0u;
    __syncthreads();
    u32 *a = sa, *b = sb;
    for (int off = 1; off < 512; off <<= 1){
        u32 v = a[t]; if (t >= off) v += a[t - off];
        b[t] = v; __syncthreads();
        u32* tmp = a; a = b; b = tmp;
    }
    if (t < NBKT){
        u32 ex = t ? a[t - 1] : 0u;
        base[t] = ex; nxt[t] = ex;
        if (t == NBKT - 1) base[NBKT] = a[t];
    }
}

// ----- phase 1: append 8B records, LDS-privatized allocation per block
__global__ __launch_bounds__(256) void bucket1_kernel(const int* __restrict__ eidx, const u16* __restrict__ score,
        u32* __restrict__ bnext, uint2* __restrict__ Bd, uint2* __restrict__ Bs){
    __shared__ u32 hd[NBKT], hs[NBKT];      // per-block counts
    __shared__ u32 rbd[NBKT], rbs[NBKT];    // reserved global bases
    __shared__ u32 ld[NBKT], ls[NBKT];      // local ranks
    const int tid = threadIdx.x;
    for (int i = tid; i < NBKT; i += 256){ hd[i] = 0u; hs[i] = 0u; ld[i] = 0u; ls[i] = 0u; }
    __syncthreads();
    const int e0 = blockIdx.x * EPB;
    for (int i = tid; i < EPB; i += 256){
        int e = e0 + i;
        if (e < N_EDGES){
            atomicAdd(&hd[eidx[N_EDGES + e] >> 7], 1u);
            atomicAdd(&hs[eidx[e] >> 7], 1u);
        }
    }
    __syncthreads();
    for (int i = tid; i < NBKT; i += 256){
        rbd[i] = hd[i] ? atomicAdd(&bnext[i], hd[i]) : 0u;
        rbs[i] = hs[i] ? atomicAdd(&bnext[NBKT + i], hs[i]) : 0u;
    }
    __syncthreads();
    for (int i = tid; i < EPB; i += 256){
        int e = e0 + i;
        if (e < N_EDGES){
            int src = eidx[e], dst = eidx[N_EDGES + e];
            u32 sc = (u32)score[e] << 16;
            int bd = dst >> 7;
            u32 r = atomicAdd(&ld[bd], 1u);
            Bd[rbd[bd] + r] = make_uint2(sc | (u32)src, (u32)(dst & 127));
            int bs_ = src >> 7;
            u32 r2 = atomicAdd(&ls[bs_], 1u);
            Bs[rbs[bs_] + r2] = make_uint2(sc | (u32)dst, (u32)(src & 127));
        }
    }
}

// -------------------- phase 2: per-bucket local CSR build (no global atomics)
__global__ __launch_bounds__(256) void bucket2_kernel(const uint2* __restrict__ Bd, const uint2* __restrict__ Bs,
        const u32* __restrict__ bbase,
        u32* __restrict__ cnt_dst, u32* __restrict__ start_dst,
        u32* __restrict__ cnt_src, u32* __restrict__ start_src,
        u32* __restrict__ in_pay, u32* __restrict__ out_pay){
    __shared__ u32 pays[MAXREC];
    __shared__ u16 locs[MAXREC];
    __shared__ u32 hist[BKT], nxt[BKT], pref[BKT];
    const int tid = threadIdx.x;
    const int side = blockIdx.x >= NBKT ? 1 : 0;
    const int b = side ? blockIdx.x - NBKT : blockIdx.x;
    const uint2* __restrict__ B = side ? Bs : Bd;
    const u32* bb = bbase + side * (NBKT + 1);
    const u32 base = bb[b];
    const u32 nrec = bb[b + 1] - base;
    u32* cnto = side ? cnt_src : cnt_dst;
    u32* sto  = side ? start_src : start_dst;
    u32* payo = side ? out_pay : in_pay;
    for (int i = tid; i < BKT; i += 256) hist[i] = 0u;
    __syncthreads();
    for (u32 i = tid; i < nrec; i += 256){
        uint2 r = B[base + i];
        if (i < MAXREC){ pays[i] = r.x; locs[i] = (u16)r.y; }
        atomicAdd(&hist[r.y & (BKT - 1)], 1u);
    }
    __syncthreads();
    if (tid < BKT) pref[tid] = hist[tid];
    __syncthreads();
    for (int off = 1; off < BKT; off <<= 1){
        u32 v = 0;
        if (tid < BKT){ v = pref[tid]; if (tid >= off) v += pref[tid - off]; }
        __syncthreads();
        if (tid < BKT) pref[tid] = v;
        __syncthreads();
    }
    if (tid < BKT){
        u32 ex = tid ? pref[tid - 1] : 0u;
        u32 gstart = base + ex;
        nxt[tid] = gstart;
        int node = b * BKT + tid;
        if (node < N_NODES){ cnto[node] = hist[tid]; sto[node] = gstart; }
    }
    __syncthreads();
    for (u32 i = tid; i < nrec; i += 256){
        u32 pay; int loc;
        if (i < MAXREC){ pay = pays[i]; loc = locs[i]; }
        else { uint2 r = B[base + i]; pay = r.x; loc = (int)(r.y & (BKT - 1)); }
        u32 pos = atomicAdd(&nxt[loc], 1u);
        payo[pos] = pay;
    }
}

// ------------------- gather weighted raw-x sums (fp8 table, 8-deep ILP)
__global__ __launch_bounds__(256) void gather_kernel(const u32* __restrict__ xf8,
        const u32* __restrict__ in_pay, const u32* __restrict__ out_pay,
        const u32* __restrict__ cnt_dst, const u32* __restrict__ start_dst,
        const u32* __restrict__ cnt_src, const u32* __restrict__ start_src,
        u32* __restrict__ Y, float* __restrict__ ssin, float* __restrict__ ssout){
    const int w = threadIdx.x >> 6, lane = threadIdx.x & 63;
    const int node = blockIdx.x * 2 + (w >> 1);
    const int dir = w & 1;
    const u32* __restrict__ pay = dir ? out_pay : in_pay;
    const u32 deg = dir ? cnt_src[node] : cnt_dst[node];
    const u32 st  = dir ? start_src[node] : start_dst[node];
    const int half = lane >> 5, l5 = lane & 31;
    float2v AL = {0.f, 0.f}, AH = {0.f, 0.f};
    float ss = 0.f;
    u32 j = (u32)half;
    for (; j + 14 < deg; j += 16){
        u32 p0 = pay[st+j],    p1 = pay[st+j+2],  p2 = pay[st+j+4],  p3 = pay[st+j+6];
        u32 p4 = pay[st+j+8],  p5 = pay[st+j+10], p6 = pay[st+j+12], p7 = pay[st+j+14];
        u32 v0 = xf8[(p0 & 0xffffu)*32 + l5], v1 = xf8[(p1 & 0xffffu)*32 + l5];
        u32 v2 = xf8[(p2 & 0xffffu)*32 + l5], v3 = xf8[(p3 & 0xffffu)*32 + l5];
        u32 v4 = xf8[(p4 & 0xffffu)*32 + l5], v5 = xf8[(p5 & 0xffffu)*32 + l5];
        u32 v6 = xf8[(p6 & 0xffffu)*32 + l5], v7 = xf8[(p7 & 0xffffu)*32 + l5];
        float s0 = __uint_as_float(p0 & 0xffff0000u), s1 = __uint_as_float(p1 & 0xffff0000u);
        float s2 = __uint_as_float(p2 & 0xffff0000u), s3 = __uint_as_float(p3 & 0xffff0000u);
        float s4 = __uint_as_float(p4 & 0xffff0000u), s5 = __uint_as_float(p5 & 0xffff0000u);
        float s6 = __uint_as_float(p6 & 0xffff0000u), s7 = __uint_as_float(p7 & 0xffff0000u);
        AL += dec2_word<false>(v0) * s0;  AH += dec2_word<true>(v0) * s0;
        AL += dec2_word<false>(v1) * s1;  AH += dec2_word<true>(v1) * s1;
        AL += dec2_word<false>(v2) * s2;  AH += dec2_word<true>(v2) * s2;
        AL += dec2_word<false>(v3) * s3;  AH += dec2_word<true>(v3) * s3;
        AL += dec2_word<false>(v4) * s4;  AH += dec2_word<true>(v4) * s4;
        AL += dec2_word<false>(v5) * s5;  AH += dec2_word<true>(v5) * s5;
        AL += dec2_word<false>(v6) * s6;  AH += dec2_word<true>(v6) * s6;
        AL += dec2_word<false>(v7) * s7;  AH += dec2_word<true>(v7) * s7;
        ss += s0 + s1 + s2 + s3 + s4 + s5 + s6 + s7;
    }
    for (; j + 6 < deg; j += 8){
        u32 p0 = pay[st+j], p1 = pay[st+j+2], p2 = pay[st+j+4], p3 = pay[st+j+6];
        u32 v0 = xf8[(p0 & 0xffffu)*32 + l5], v1 = xf8[(p1 & 0xffffu)*32 + l5];
        u32 v2 = xf8[(p2 & 0xffffu)*32 + l5], v3 = xf8[(p3 & 0xffffu)*32 + l5];
        float s0 = __uint_as_float(p0 & 0xffff0000u), s1 = __uint_as_float(p1 & 0xffff0000u);
        float s2 = __uint_as_float(p2 & 0xffff0000u), s3 = __uint_as_float(p3 & 0xffff0000u);
        AL += dec2_word<false>(v0) * s0;  AH += dec2_word<true>(v0) * s0;
        AL += dec2_word<false>(v1) * s1;  AH += dec2_word<true>(v1) * s1;
        AL += dec2_word<false>(v2) * s2;  AH += dec2_word<true>(v2) * s2;
        AL += dec2_word<false>(v3) * s3;  AH += dec2_word<true>(v3) * s3;
        ss += s0 + s1 + s2 + s3;
    }
    for (; j < deg; j += 2){
        u32 pl = pay[st + j];
        u32 v = xf8[(pl & 0xffffu)*32 + l5];
        float sc = __uint_as_float(pl & 0xffff0000u);
        AL += dec2_word<false>(v) * sc;
        AH += dec2_word<true>(v) * sc;
        ss += sc;
    }
    float a0 = AL[0], a1 = AL[1], a2 = AH[0], a3 = AH[1];
    a0 += __shfl_xor(a0, 32, 64);
    a1 += __shfl_xor(a1, 32, 64);
    a2 += __shfl_xor(a2, 32, 64);
    a3 += __shfl_xor(a3, 32, 64);
    ss += __shfl_xor(ss, 32, 64);
    if (half == 0){
        uint2 o;
        o.x = (u32)f2bf(a0) | ((u32)f2bf(a1) << 16);
        o.y = (u32)f2bf(a2) | ((u32)f2bf(a3) << 16);
        *(uint2*)(Y + node * 128 + dir * 64 + l5 * 2) = o;
    }
    if (lane == 0){
        if (dir) ssout[node] = ss; else ssin[node] = ss;
    }
}

// ------------- finale: msg GEMMs + normalize + gate MLP + fuse + residual
__global__ __launch_bounds__(256) void finale_mfma_kernel(const u32* __restrict__ Yw,
        const float* __restrict__ x,
        const u16* __restrict__ pkM, const u16* __restrict__ pkG,
        const float* __restrict__ b_s2d, const float* __restrict__ b_d2s,
        const float* __restrict__ ssin, const float* __restrict__ ssout,
        const u32* __restrict__ cnt_dst, const u32* __restrict__ cnt_src,
        const float* __restrict__ b_g1, const float* __restrict__ w_g2, const float* __restrict__ b_g2,
        float* __restrict__ out){
    __shared__ u32 Hsh[16][132];
    __shared__ float part[16][17];
    __shared__ float gl[16];
    const int tid = threadIdx.x;
    const int w = tid >> 6, l = tid & 63;
    const int l16 = l & 15, lg = l >> 4;
    const int n0 = blockIdx.x * 16;
    const int node = n0 + l16;
    const int dir = w >> 1;
    const int cb = (w & 1) * 64;
    const u16* Yh = (const u16*)Yw;
    bf16x8 yf[4];
    #pragma unroll
    for (int ks = 0; ks < 4; ks++)
        yf[ks] = *(const bf16x8*)(Yh + node * 256 + dir * 128 + ks * 32 + lg * 8);
    const float ssv  = dir ? ssout[node] : ssin[node];
    const float dinv = 1.f / fmaxf((float)(dir ? cnt_src[node] : cnt_dst[node]), 1.f);
    const float* bv = dir ? b_d2s : b_s2d;
    #pragma unroll
    for (int ct = 0; ct < 4; ct++){
        const int chl = cb + ct * 16;
        f32x4 acc = {0.f, 0.f, 0.f, 0.f};
        #pragma unroll
        for (int ks = 0; ks < 4; ks++){
            bf16x8 a = *(const bf16x8*)(pkM + ((ks * 256 + dir * 128 + chl + l16) * 4 + lg) * 8);
            acc = __builtin_amdgcn_mfma_f32_16x16x32_bf16(a, yf[ks], acc, 0, 0, 0);
        }
        const int chb = chl + lg * 4;
        float h0 = (acc[0] + ssv * bv[chb])     * dinv;
        float h1 = (acc[1] + ssv * bv[chb + 1]) * dinv;
        float h2 = (acc[2] + ssv * bv[chb + 2]) * dinv;
        float h3 = (acc[3] + ssv * bv[chb + 3]) * dinv;
        const int wi = (dir * 128 + chb) >> 1;
        Hsh[l16][wi]     = (u32)f2bf(h0) | ((u32)f2bf(h1) << 16);
        Hsh[l16][wi + 1] = (u32)f2bf(h2) | ((u32)f2bf(h3) << 16);
    }
    __syncthreads();
    bf16x8 hb[8];
    #pragma unroll
    for (int ks = 0; ks < 8; ks++)
        hb[ks] = *(const bf16x8*)((const u16*)&Hsh[l16][0] + ks * 32 + lg * 8);
    float p = 0.f;
    #pragma unroll
    for (int ct2 = 0; ct2 < 2; ct2++){
        const int oc0 = w * 32 + ct2 * 16;
        f32x4 acc = {0.f, 0.f, 0.f, 0.f};
        #pragma unroll
        for (int ks = 0; ks < 8; ks++){
            bf16x8 a = *(const bf16x8*)(pkG + ((ks * 128 + oc0 + l16) * 4 + lg) * 8);
            acc = __builtin_amdgcn_mfma_f32_16x16x32_bf16(a, hb[ks], acc, 0, 0, 0);
        }
        const int ob = oc0 + lg * 4;
        #pragma unroll
        for (int r = 0; r < 4; r++)
            p += fmaxf(acc[r] + b_g1[ob + r], 0.f) * w_g2[ob + r];
    }
    part[l16][w * 4 + lg] = p;
    __syncthreads();
    if (tid < 16){
        float s = 0.f;
        #pragma unroll
        for (int i = 0; i < 16; i++) s += part[tid][i];
        gl[tid] = 1.f / (1.f + __expf(-(s + b_g2[0])));
    }
    __syncthreads();
    {
        const int nn = tid >> 4, o = (tid & 15) * 8;
        const float gv = gl[nn];
        const int gbase = (n0 + nn) * 128 + o;
        float4 x0 = *(const float4*)(x + gbase);
        float4 x1 = *(const float4*)(x + gbase + 4);
        float r[8];
        #pragma unroll
        for (int t = 0; t < 4; t++){
            u32 hi = Hsh[nn][(o >> 1) + t];
            u32 ho = Hsh[nn][64 + (o >> 1) + t];
            r[2*t]   = gv * bf_lo(hi) + (1.f - gv) * bf_lo(ho);
            r[2*t+1] = gv * bf_hi(hi) + (1.f - gv) * bf_hi(ho);
        }
        *(float4*)(out + gbase)     = make_float4(r[0]+x0.x, r[1]+x0.y, r[2]+x0.z, r[3]+x0.w);
        *(float4*)(out + gbase + 4) = make_float4(r[4]+x1.x, r[5]+x1.y, r[6]+x1.z, r[7]+x1.w);
    }
}

extern "C" void kernel_launch(void* const* d_in, const int* in_sizes, int n_in,
                              void* d_out, int out_size, void* d_ws, size_t ws_size,
                              hipStream_t stream){
    const float* x     = (const float*)d_in[0];
    const int*   ei    = (const int*)d_in[1];          // int32 (JAX x64 off)
    const float* w_s2d = (const float*)d_in[2];
    const float* b_s2d = (const float*)d_in[3];
    const float* w_d2s = (const float*)d_in[4];
    const float* b_d2s = (const float*)d_in[5];
    const float* w_e1  = (const float*)d_in[6];
    const float* b_e1  = (const float*)d_in[7];
    const float* w_e2  = (const float*)d_in[8];
    const float* b_e2  = (const float*)d_in[9];
    const float* w_g1  = (const float*)d_in[10];
    const float* b_g1  = (const float*)d_in[11];
    const float* w_g2  = (const float*)d_in[12];
    const float* b_g2  = (const float*)d_in[13];
    float* out = (float*)d_out;
    u32*   T1  = (u32*)d_out;                    // fp8 [A|B], first 12.8 MB
    uint2* Bd  = (uint2*)((u32*)d_out + 3200000); // second half: 6.4 MB
    uint2* Bs  = Bd + N_EDGES;                    // + 6.4 MB (= 25.6 MB total)
    u32*   Y   = (u32*)d_out;                    // bf16 [y_in|y_out] (after bucket2)

    char* ws = (char*)d_ws;
    size_t off = 0;
    #define TAKE(name, bytes) char* name = ws + off; off += (((size_t)(bytes)) + 511) & ~(size_t)511;
    TAKE(pk1_b,   32768 * 2)
    TAKE(pkM_b,   32768 * 2)
    TAKE(pkG_b,   32768 * 2)
    TAKE(bias1_b, 256 * 4)
    TAKE(xb_b,    (size_t)N_NODES * 128 * 2)  // x in bf16 (proj), 12.8 MB
    TAKE(xf8_b,   (size_t)N_NODES * 128)      // x in fp8 (gather), 6.4 MB
    TAKE(score_b, (size_t)N_EDGES * 2)
    TAKE(bcnt_b,  (size_t)2 * NBKT * 4)
    TAKE(bbase_b, (size_t)2 * (NBKT + 1) * 4)
    TAKE(bnext_b, (size_t)2 * NBKT * 4)
    TAKE(cnt_b,   (size_t)2 * N_NODES * 4)    // cnt_dst | cnt_src
    TAKE(sd_b,    (size_t)N_NODES * 4)        // start_dst
    TAKE(ss2_b,   (size_t)N_NODES * 4)        // start_src
    TAKE(ipay_b,  (size_t)N_EDGES * 4)
    TAKE(opay_b,  (size_t)N_EDGES * 4)
    TAKE(ssin_b,  (size_t)N_NODES * 4)
    TAKE(ssout_b, (size_t)N_NODES * 4)
    #undef TAKE
    (void)ws_size; (void)in_sizes; (void)n_in; (void)out_size;
    // total ~29 MB

    hipMemsetAsync(bcnt_b, 0, (size_t)2 * NBKT * 4, stream);
    setup_kernel<<<XCBLK + 386 + CNTBLK, 256, 0, stream>>>(x, w_s2d, w_d2s, w_e1, w_g1, b_e1, ei,
        (uint2*)xb_b, (u32*)xf8_b, (u16*)pk1_b, (u16*)pkM_b, (u16*)pkG_b,
        (float*)bias1_b, (u32*)bcnt_b);
    proj_mfma_kernel<<<N_NODES / 16, 256, 0, stream>>>((const u16*)xb_b,
        (const u16*)pk1_b, (const float*)bias1_b, T1);
    edge_score_kernel<<<N_EDGES / 16, 256, 0, stream>>>((const u32*)T1, ei, w_e2, b_e2,
        (u16*)score_b);
    bucket_scan_kernel<<<2, 512, 0, stream>>>((const u32*)bcnt_b, (u32*)bbase_b, (u32*)bnext_b);
    bucket1_kernel<<<(N_EDGES + EPB - 1) / EPB, 256, 0, stream>>>(ei, (const u16*)score_b,
        (u32*)bnext_b, Bd, Bs);
    bucket2_kernel<<<2 * NBKT, 256, 0, stream>>>(Bd, Bs, (const u32*)bbase_b,
        (u32*)cnt_b, (u32*)sd_b, (u32*)cnt_b + N_NODES, (u32*)ss2_b,
        (u32*)ipay_b, (u32*)opay_b);
    gather_kernel<<<N_NODES / 2, 256, 0, stream>>>((const u32*)xf8_b,
        (const u32*)ipay_b, (const u32*)opay_b,
        (const u32*)cnt_b, (const u32*)sd_b, (const u32*)cnt_b + N_NODES, (const u32*)ss2_b,
        Y, (float*)ssin_b, (float*)ssout_b);
    finale_mfma_kernel<<<N_NODES / 16, 256, 0, stream>>>((const u32*)Y, x,
        (const u16*)pkM_b, (const u16*)pkG_b, b_s2d, b_d2s,
        (const float*)ssin_b, (const float*)ssout_b,
        (const u32*)cnt_b, (const u32*)cnt_b + N_NODES,
        b_g1, w_g2, b_g2, out);
}

// Round 15
// 218.190 us; speedup vs baseline: 1.3283x; 1.0318x over previous
//
#include <hip/hip_runtime.h>

#define N_NODES 50000
#define N_EDGES 800000
#define NBKT 391          // ceil(50000/128) buckets of 128 nodes
#define BKT 128
#define MAXREC 2560       // bucket capacity in LDS (mean 2046, +11 sigma)
#define EPB 4096          // edges per block in count/bucket1
#define XCBLK 6250        // xcast blocks: N_NODES*128/4/256
#define CNTBLK 196        // count blocks: ceil(800000/4096)

typedef unsigned int u32;
typedef unsigned short u16;
typedef __attribute__((ext_vector_type(2))) float float2v;
typedef __attribute__((ext_vector_type(8))) short bf16x8;
typedef __attribute__((ext_vector_type(4))) float f32x4;

__device__ __forceinline__ float bf_lo(u32 v){ return __uint_as_float(v << 16); }
__device__ __forceinline__ float bf_hi(u32 v){ return __uint_as_float(v & 0xffff0000u); }
__device__ __forceinline__ u16 f2bf(float f){
    u32 u = __float_as_uint(f);
    u += 0x7fffu + ((u >> 16) & 1u);     // round-to-nearest-even
    return (u16)(u >> 16);
}

#if __has_builtin(__builtin_amdgcn_cvt_pk_f32_fp8) && __has_builtin(__builtin_amdgcn_cvt_pk_fp8_f32)
#define HW_FP8 1
#else
#define HW_FP8 0
#endif

__device__ __forceinline__ u32 enc1_e4m3(float f){
    u32 u = __float_as_uint(f);
    u32 s = (u >> 24) & 0x80u;
    u32 a = u & 0x7fffffffu;
    if (a >= 0x43e00000u) return s | 0x7eu;          // >= 448 -> sat
    if (a < 0x3c800000u){                            // < 2^-6 -> denormal (m * 2^-9)
        float af = __uint_as_float(a) * 512.f;
        u32 m = (u32)(af + 0.5f);
        return s | m;
    }
    int e = (int)(a >> 23) - 127;
    u32 mant = (a >> 20) & 7u;
    u32 rnd = (a >> 19) & 1u;
    u32 sticky = (a & 0x7ffffu) ? 1u : 0u;
    u32 code = ((u32)(e + 7) << 3) | mant;
    code += (rnd & (sticky | (mant & 1u)));
    if (code > 0x7eu) code = 0x7eu;
    return s | code;
}

template<bool HI>
__device__ __forceinline__ float2v dec2_word(u32 v){
#if HW_FP8
    return __builtin_amdgcn_cvt_pk_f32_fp8(v, HI);
#else
    u32 v16 = HI ? (v >> 16) : (v & 0xffffu);
    float2v r;
    #pragma unroll
    for (int t = 0; t < 2; t++){
        u32 b = (v16 >> (8 * t)) & 0xffu;
        u32 e = (b >> 3) & 15u, m = b & 7u;
        float fv = e ? __uint_as_float(((e + 120u) << 23) | (m << 20)) : (float)m * 0.001953125f;
        r[t] = (b & 0x80u) ? -fv : fv;
    }
    return r;
#endif
}
__device__ __forceinline__ u32 encpk_lo(float a, float b, u32 old){
#if HW_FP8
    return (u32)__builtin_amdgcn_cvt_pk_fp8_f32(a, b, (int)old, false);
#else
    return (old & 0xffff0000u) | enc1_e4m3(a) | (enc1_e4m3(b) << 8);
#endif
}
__device__ __forceinline__ u32 encpk_hi(float a, float b, u32 old){
#if HW_FP8
    return (u32)__builtin_amdgcn_cvt_pk_fp8_f32(a, b, (int)old, true);
#else
    return (old & 0x0000ffffu) | (enc1_e4m3(a) << 16) | (enc1_e4m3(b) << 24);
#endif
}

// --------- setup: xcast | weight prep | bucket count histograms (persisted)
__global__ __launch_bounds__(256) void setup_kernel(const float* __restrict__ x,
        const float* __restrict__ w_s2d, const float* __restrict__ w_d2s,
        const float* __restrict__ w_e1, const float* __restrict__ w_g1,
        const float* __restrict__ b_e1, const int* __restrict__ eidx,
        uint2* __restrict__ xb2, u32* __restrict__ xf8,
        u16* __restrict__ pk1, u16* __restrict__ pkM,
        u16* __restrict__ pkG, float* __restrict__ bias1,
        u32* __restrict__ bcnt, u32* __restrict__ bhist){
    const int blk = blockIdx.x, tid = threadIdx.x;
    if (blk < XCBLK){
        int i = blk * 256 + tid;                 // one float4 (4 elems) per thread
        float4 v = ((const float4*)x)[i];
        uint2 o;
        o.x = (u32)f2bf(v.x) | ((u32)f2bf(v.y) << 16);
        o.y = (u32)f2bf(v.z) | ((u32)f2bf(v.w) << 16);
        xb2[i] = o;
        u32 w8 = encpk_lo(v.x, v.y, 0u);
        xf8[i] = encpk_hi(v.z, v.w, w8);
    } else if (blk < XCBLK + 386){
        int idx = (blk - XCBLK) * 256 + tid;
        if (idx < 32768){
            int j = idx & 7, g = (idx >> 3) & 3, ch = (idx >> 5) & 255, ks = idx >> 13;
            int k = ks * 32 + g * 8 + j;
            float v = (ch < 128) ? w_e1[k * 128 + ch] : w_e1[(128 + k) * 128 + (ch - 128)];
            pk1[idx] = f2bf(v);
        } else if (idx < 65536){
            int i2 = idx - 32768;
            int j = i2 & 7, g = (i2 >> 3) & 3, ch = (i2 >> 5) & 255, ks = i2 >> 13;
            int k = ks * 32 + g * 8 + j;
            float v = (ch < 128) ? w_s2d[k * 128 + ch] : w_d2s[k * 128 + (ch - 128)];
            pkM[i2] = f2bf(v);
        } else if (idx < 98304){
            int i2 = idx - 65536;
            int j = i2 & 7, g = (i2 >> 3) & 3, oc = (i2 >> 5) & 127, ks = i2 >> 12;
            int k = ks * 32 + g * 8 + j;
            pkG[i2] = f2bf(w_g1[k * 128 + oc]);
        } else if (idx < 98560){
            int o = idx - 98304;
            bias1[o] = (o < 128) ? b_e1[o] : 0.f;
        }
    } else {
        // count blocks: LDS-privatized bucket histogram; persist per-block hist
        __shared__ u32 h[2 * NBKT];
        const int cb = blk - XCBLK - 386;
        for (int i = tid; i < 2 * NBKT; i += 256) h[i] = 0u;
        __syncthreads();
        const int e0 = cb * EPB;
        for (int i = tid; i < EPB; i += 256){
            int e = e0 + i;
            if (e < N_EDGES){
                atomicAdd(&h[eidx[N_EDGES + e] >> 7], 1u);          // dst side
                atomicAdd(&h[NBKT + (eidx[e] >> 7)], 1u);           // src side
            }
        }
        __syncthreads();
        for (int i = tid; i < 2 * NBKT; i += 256){
            u32 v = h[i];
            bhist[cb * 2 * NBKT + i] = v;
            if (v) atomicAdd(&bcnt[i], v);
        }
    }
}

// ----------------------- score projections T1 = [A|B] fp8, via MFMA
__global__ __launch_bounds__(256) void proj_mfma_kernel(const u16* __restrict__ xb16,
        const u16* __restrict__ pk1, const float* __restrict__ bias1, u32* __restrict__ T1){
    const int tid = threadIdx.x;
    const int w = tid >> 6, l = tid & 63;
    const int l16 = l & 15, lg = l >> 4;
    const int n0 = blockIdx.x * 16;
    const int node = n0 + l16;
    bf16x8 bx[4];
    #pragma unroll
    for (int ks = 0; ks < 4; ks++)
        bx[ks] = *(const bf16x8*)(xb16 + node * 128 + ks * 32 + lg * 8);
    #pragma unroll
    for (int ct = 0; ct < 4; ct++){
        const int ch0 = w * 64 + ct * 16;
        f32x4 acc = {0.f, 0.f, 0.f, 0.f};
        #pragma unroll
        for (int ks = 0; ks < 4; ks++){
            bf16x8 a = *(const bf16x8*)(pk1 + ((ks * 256 + ch0 + l16) * 4 + lg) * 8);
            acc = __builtin_amdgcn_mfma_f32_16x16x32_bf16(a, bx[ks], acc, 0, 0, 0);
        }
        const int chb = ch0 + lg * 4;
        float f0 = acc[0] + bias1[chb],     f1 = acc[1] + bias1[chb + 1];
        float f2 = acc[2] + bias1[chb + 2], f3 = acc[3] + bias1[chb + 3];
        u32 wd = encpk_lo(f0, f1, 0u);
        wd = encpk_hi(f2, f3, wd);
        T1[node * 64 + (chb >> 2)] = wd;
    }
}

// ------------------- edge scores (no atomics, 8 lanes/edge, uint4 loads)
__global__ __launch_bounds__(256) void edge_score_kernel(const u32* __restrict__ T1w, const int* __restrict__ eidx,
        const float* __restrict__ w_e2, const float* __restrict__ b_e2,
        u16* __restrict__ score){
    const int l8 = threadIdx.x & 7;
    const int e = blockIdx.x * 32 + (threadIdx.x >> 3);
    const int src = eidx[e];
    const int dst = eidx[N_EDGES + e];
    const uint4 a8 = *(const uint4*)(T1w + src * 64 + l8 * 4);
    const uint4 b8 = *(const uint4*)(T1w + dst * 64 + 32 + l8 * 4);
    const float2v* wv = (const float2v*)(w_e2 + l8 * 16);
    const float2v zero = {0.f, 0.f};
    float2v acc = {0.f, 0.f};
    float2v t;
    t = __builtin_elementwise_max(dec2_word<false>(a8.x) + dec2_word<false>(b8.x), zero); acc += t * wv[0];
    t = __builtin_elementwise_max(dec2_word<true >(a8.x) + dec2_word<true >(b8.x), zero); acc += t * wv[1];
    t = __builtin_elementwise_max(dec2_word<false>(a8.y) + dec2_word<false>(b8.y), zero); acc += t * wv[2];
    t = __builtin_elementwise_max(dec2_word<true >(a8.y) + dec2_word<true >(b8.y), zero); acc += t * wv[3];
    t = __builtin_elementwise_max(dec2_word<false>(a8.z) + dec2_word<false>(b8.z), zero); acc += t * wv[4];
    t = __builtin_elementwise_max(dec2_word<true >(a8.z) + dec2_word<true >(b8.z), zero); acc += t * wv[5];
    t = __builtin_elementwise_max(dec2_word<false>(a8.w) + dec2_word<false>(b8.w), zero); acc += t * wv[6];
    t = __builtin_elementwise_max(dec2_word<true >(a8.w) + dec2_word<true >(b8.w), zero); acc += t * wv[7];
    float p = acc[0] + acc[1];
    p += __shfl_xor(p, 1, 64);
    p += __shfl_xor(p, 2, 64);
    p += __shfl_xor(p, 4, 64);
    if (l8 == 0){
        float sc = 1.f / (1.f + __expf(-(p + b_e2[0])));
        score[e] = f2bf(sc);
    }
}

// --------- bucket scan (bin bases) + per-block base table rb[blk][bin]
__global__ __launch_bounds__(512) void bucket_scan_kernel(const u32* __restrict__ bcnt,
        const u32* __restrict__ bhist, u32* __restrict__ bbase, u32* __restrict__ rb){
    __shared__ u32 sa[512], sb[512];
    const int t = threadIdx.x;
    const int side = blockIdx.x;
    const u32* c = bcnt + side * NBKT;
    u32* base = bbase + side * (NBKT + 1);
    sa[t] = (t < NBKT) ? c[t] : 0u;
    __syncthreads();
    u32 *a = sa, *b = sb;
    for (int off = 1; off < 512; off <<= 1){
        u32 v = a[t]; if (t >= off) v += a[t - off];
        b[t] = v; __syncthreads();
        u32* tmp = a; a = b; b = tmp;
    }
    u32 ex = 0;
    if (t < NBKT){
        ex = t ? a[t - 1] : 0u;
        base[t] = ex;
        if (t == NBKT - 1) base[NBKT] = a[t];
    }
    // phase B: per-block exclusive bases for this side's bins
    if (t < NBKT){
        u32 run = ex;
        const int col = side * NBKT + t;
        for (int cb = 0; cb < CNTBLK; cb++){
            u32 hv = bhist[cb * 2 * NBKT + col];
            rb[cb * 2 * NBKT + col] = run;
            run += hv;
        }
    }
}

// ----- phase 1: append 8B records at precomputed per-block bases
__global__ __launch_bounds__(256) void bucket1_kernel(const int* __restrict__ eidx, const u16* __restrict__ score,
        const u32* __restrict__ rb, uint2* __restrict__ Bd, uint2* __restrict__ Bs){
    __shared__ u32 rbl[2 * NBKT];           // this block's write bases
    __shared__ u32 ld[NBKT], ls[NBKT];      // local ranks
    const int tid = threadIdx.x;
    for (int i = tid; i < 2 * NBKT; i += 256) rbl[i] = rb[blockIdx.x * 2 * NBKT + i];
    for (int i = tid; i < NBKT; i += 256){ ld[i] = 0u; ls[i] = 0u; }
    __syncthreads();
    const int e0 = blockIdx.x * EPB;
    for (int i = tid; i < EPB; i += 256){
        int e = e0 + i;
        if (e < N_EDGES){
            int src = eidx[e], dst = eidx[N_EDGES + e];
            u32 sc = (u32)score[e] << 16;
            int bd = dst >> 7;
            u32 r = atomicAdd(&ld[bd], 1u);
            Bd[rbl[bd] + r] = make_uint2(sc | (u32)src, (u32)(dst & 127));
            int bs_ = src >> 7;
            u32 r2 = atomicAdd(&ls[bs_], 1u);
            Bs[rbl[NBKT + bs_] + r2] = make_uint2(sc | (u32)dst, (u32)(src & 127));
        }
    }
}

// -------------------- phase 2: per-bucket local CSR build (no global atomics)
__global__ __launch_bounds__(256) void bucket2_kernel(const uint2* __restrict__ Bd, const uint2* __restrict__ Bs,
        const u32* __restrict__ bbase,
        u32* __restrict__ cnt_dst, u32* __restrict__ start_dst,
        u32* __restrict__ cnt_src, u32* __restrict__ start_src,
        u32* __restrict__ in_pay, u32* __restrict__ out_pay){
    __shared__ u32 pays[MAXREC];
    __shared__ u16 locs[MAXREC];
    __shared__ u32 hist[BKT], nxt[BKT], pref[BKT];
    const int tid = threadIdx.x;
    const int side = blockIdx.x >= NBKT ? 1 : 0;
    const int b = side ? blockIdx.x - NBKT : blockIdx.x;
    const uint2* __restrict__ B = side ? Bs : Bd;
    const u32* bb = bbase + side * (NBKT + 1);
    const u32 base = bb[b];
    const u32 nrec = bb[b + 1] - base;
    u32* cnto = side ? cnt_src : cnt_dst;
    u32* sto  = side ? start_src : start_dst;
    u32* payo = side ? out_pay : in_pay;
    for (int i = tid; i < BKT; i += 256) hist[i] = 0u;
    __syncthreads();
    for (u32 i = tid; i < nrec; i += 256){
        uint2 r = B[base + i];
        if (i < MAXREC){ pays[i] = r.x; locs[i] = (u16)r.y; }
        atomicAdd(&hist[r.y & (BKT - 1)], 1u);
    }
    __syncthreads();
    if (tid < BKT) pref[tid] = hist[tid];
    __syncthreads();
    for (int off = 1; off < BKT; off <<= 1){
        u32 v = 0;
        if (tid < BKT){ v = pref[tid]; if (tid >= off) v += pref[tid - off]; }
        __syncthreads();
        if (tid < BKT) pref[tid] = v;
        __syncthreads();
    }
    if (tid < BKT){
        u32 ex = tid ? pref[tid - 1] : 0u;
        u32 gstart = base + ex;
        nxt[tid] = gstart;
        int node = b * BKT + tid;
        if (node < N_NODES){ cnto[node] = hist[tid]; sto[node] = gstart; }
    }
    __syncthreads();
    for (u32 i = tid; i < nrec; i += 256){
        u32 pay; int loc;
        if (i < MAXREC){ pay = pays[i]; loc = locs[i]; }
        else { uint2 r = B[base + i]; pay = r.x; loc = (int)(r.y & (BKT - 1)); }
        u32 pos = atomicAdd(&nxt[loc], 1u);
        payo[pos] = pay;
    }
}

// ------------------- gather weighted raw-x sums (fp8 table, 16-deep ILP)
__global__ __launch_bounds__(256) void gather_kernel(const u32* __restrict__ xf8,
        const u32* __restrict__ in_pay, const u32* __restrict__ out_pay,
        const u32* __restrict__ cnt_dst, const u32* __restrict__ start_dst,
        const u32* __restrict__ cnt_src, const u32* __restrict__ start_src,
        u32* __restrict__ Y, float* __restrict__ ssin, float* __restrict__ ssout){
    const int w = threadIdx.x >> 6, lane = threadIdx.x & 63;
    const int node = blockIdx.x * 2 + (w >> 1);
    const int dir = w & 1;
    const u32* __restrict__ pay = dir ? out_pay : in_pay;
    const u32 deg = dir ? cnt_src[node] : cnt_dst[node];
    const u32 st  = dir ? start_src[node] : start_dst[node];
    const int half = lane >> 5, l5 = lane & 31;
    float2v AL = {0.f, 0.f}, AH = {0.f, 0.f};
    float ss = 0.f;
    u32 j = (u32)half;
    for (; j + 14 < deg; j += 16){
        u32 p0 = pay[st+j],    p1 = pay[st+j+2],  p2 = pay[st+j+4],  p3 = pay[st+j+6];
        u32 p4 = pay[st+j+8],  p5 = pay[st+j+10], p6 = pay[st+j+12], p7 = pay[st+j+14];
        u32 v0 = xf8[(p0 & 0xffffu)*32 + l5], v1 = xf8[(p1 & 0xffffu)*32 + l5];
        u32 v2 = xf8[(p2 & 0xffffu)*32 + l5], v3 = xf8[(p3 & 0xffffu)*32 + l5];
        u32 v4 = xf8[(p4 & 0xffffu)*32 + l5], v5 = xf8[(p5 & 0xffffu)*32 + l5];
        u32 v6 = xf8[(p6 & 0xffffu)*32 + l5], v7 = xf8[(p7 & 0xffffu)*32 + l5];
        float s0 = __uint_as_float(p0 & 0xffff0000u), s1 = __uint_as_float(p1 & 0xffff0000u);
        float s2 = __uint_as_float(p2 & 0xffff0000u), s3 = __uint_as_float(p3 & 0xffff0000u);
        float s4 = __uint_as_float(p4 & 0xffff0000u), s5 = __uint_as_float(p5 & 0xffff0000u);
        float s6 = __uint_as_float(p6 & 0xffff0000u), s7 = __uint_as_float(p7 & 0xffff0000u);
        AL += dec2_word<false>(v0) * s0;  AH += dec2_word<true>(v0) * s0;
        AL += dec2_word<false>(v1) * s1;  AH += dec2_word<true>(v1) * s1;
        AL += dec2_word<false>(v2) * s2;  AH += dec2_word<true>(v2) * s2;
        AL += dec2_word<false>(v3) * s3;  AH += dec2_word<true>(v3) * s3;
        AL += dec2_word<false>(v4) * s4;  AH += dec2_word<true>(v4) * s4;
        AL += dec2_word<false>(v5) * s5;  AH += dec2_word<true>(v5) * s5;
        AL += dec2_word<false>(v6) * s6;  AH += dec2_word<true>(v6) * s6;
        AL += dec2_word<false>(v7) * s7;  AH += dec2_word<true>(v7) * s7;
        ss += s0 + s1 + s2 + s3 + s4 + s5 + s6 + s7;
    }
    for (; j + 6 < deg; j += 8){
        u32 p0 = pay[st+j], p1 = pay[st+j+2], p2 = pay[st+j+4], p3 = pay[st+j+6];
        u32 v0 = xf8[(p0 & 0xffffu)*32 + l5], v1 = xf8[(p1 & 0xffffu)*32 + l5];
        u32 v2 = xf8[(p2 & 0xffffu)*32 + l5], v3 = xf8[(p3 & 0xffffu)*32 + l5];
        float s0 = __uint_as_float(p0 & 0xffff0000u), s1 = __uint_as_float(p1 & 0xffff0000u);
        float s2 = __uint_as_float(p2 & 0xffff0000u), s3 = __uint_as_float(p3 & 0xffff0000u);
        AL += dec2_word<false>(v0) * s0;  AH += dec2_word<true>(v0) * s0;
        AL += dec2_word<false>(v1) * s1;  AH += dec2_word<true>(v1) * s1;
        AL += dec2_word<false>(v2) * s2;  AH += dec2_word<true>(v2) * s2;
        AL += dec2_word<false>(v3) * s3;  AH += dec2_word<true>(v3) * s3;
        ss += s0 + s1 + s2 + s3;
    }
    for (; j < deg; j += 2){
        u32 pl = pay[st + j];
        u32 v = xf8[(pl & 0xffffu)*32 + l5];
        float sc = __uint_as_float(pl & 0xffff0000u);
        AL += dec2_word<false>(v) * sc;
        AH += dec2_word<true>(v) * sc;
        ss += sc;
    }
    float a0 = AL[0], a1 = AL[1], a2 = AH[0], a3 = AH[1];
    a0 += __shfl_xor(a0, 32, 64);
    a1 += __shfl_xor(a1, 32, 64);
    a2 += __shfl_xor(a2, 32, 64);
    a3 += __shfl_xor(a3, 32, 64);
    ss += __shfl_xor(ss, 32, 64);
    if (half == 0){
        uint2 o;
        o.x = (u32)f2bf(a0) | ((u32)f2bf(a1) << 16);
        o.y = (u32)f2bf(a2) | ((u32)f2bf(a3) << 16);
        *(uint2*)(Y + node * 128 + dir * 64 + l5 * 2) = o;
    }
    if (lane == 0){
        if (dir) ssout[node] = ss; else ssin[node] = ss;
    }
}

// ------------- finale: msg GEMMs + normalize + gate MLP + fuse + residual
__global__ __launch_bounds__(256) void finale_mfma_kernel(const u32* __restrict__ Yw,
        const float* __restrict__ x,
        const u16* __restrict__ pkM, const u16* __restrict__ pkG,
        const float* __restrict__ b_s2d, const float* __restrict__ b_d2s,
        const float* __restrict__ ssin, const float* __restrict__ ssout,
        const u32* __restrict__ cnt_dst, const u32* __restrict__ cnt_src,
        const float* __restrict__ b_g1, const float* __restrict__ w_g2, const float* __restrict__ b_g2,
        float* __restrict__ out){
    __shared__ u32 Hsh[16][132];
    __shared__ float part[16][17];
    __shared__ float gl[16];
    const int tid = threadIdx.x;
    const int w = tid >> 6, l = tid & 63;
    const int l16 = l & 15, lg = l >> 4;
    const int n0 = blockIdx.x * 16;
    const int node = n0 + l16;
    const int dir = w >> 1;
    const int cb = (w & 1) * 64;
    const u16* Yh = (const u16*)Yw;
    bf16x8 yf[4];
    #pragma unroll
    for (int ks = 0; ks < 4; ks++)
        yf[ks] = *(const bf16x8*)(Yh + node * 256 + dir * 128 + ks * 32 + lg * 8);
    const float ssv  = dir ? ssout[node] : ssin[node];
    const float dinv = 1.f / fmaxf((float)(dir ? cnt_src[node] : cnt_dst[node]), 1.f);
    const float* bv = dir ? b_d2s : b_s2d;
    #pragma unroll
    for (int ct = 0; ct < 4; ct++){
        const int chl = cb + ct * 16;
        f32x4 acc = {0.f, 0.f, 0.f, 0.f};
        #pragma unroll
        for (int ks = 0; ks < 4; ks++){
            bf16x8 a = *(const bf16x8*)(pkM + ((ks * 256 + dir * 128 + chl + l16) * 4 + lg) * 8);
            acc = __builtin_amdgcn_mfma_f32_16x16x32_bf16(a, yf[ks], acc, 0, 0, 0);
        }
        const int chb = chl + lg * 4;
        float h0 = (acc[0] + ssv * bv[chb])     * dinv;
        float h1 = (acc[1] + ssv * bv[chb + 1]) * dinv;
        float h2 = (acc[2] + ssv * bv[chb + 2]) * dinv;
        float h3 = (acc[3] + ssv * bv[chb + 3]) * dinv;
        const int wi = (dir * 128 + chb) >> 1;
        Hsh[l16][wi]     = (u32)f2bf(h0) | ((u32)f2bf(h1) << 16);
        Hsh[l16][wi + 1] = (u32)f2bf(h2) | ((u32)f2bf(h3) << 16);
    }
    __syncthreads();
    bf16x8 hb[8];
    #pragma unroll
    for (int ks = 0; ks < 8; ks++)
        hb[ks] = *(const bf16x8*)((const u16*)&Hsh[l16][0] + ks * 32 + lg * 8);
    float p = 0.f;
    #pragma unroll
    for (int ct2 = 0; ct2 < 2; ct2++){
        const int oc0 = w * 32 + ct2 * 16;
        f32x4 acc = {0.f, 0.f, 0.f, 0.f};
        #pragma unroll
        for (int ks = 0; ks < 8; ks++){
            bf16x8 a = *(const bf16x8*)(pkG + ((ks * 128 + oc0 + l16) * 4 + lg) * 8);
            acc = __builtin_amdgcn_mfma_f32_16x16x32_bf16(a, hb[ks], acc, 0, 0, 0);
        }
        const int ob = oc0 + lg * 4;
        #pragma unroll
        for (int r = 0; r < 4; r++)
            p += fmaxf(acc[r] + b_g1[ob + r], 0.f) * w_g2[ob + r];
    }
    part[l16][w * 4 + lg] = p;
    __syncthreads();
    if (tid < 16){
        float s = 0.f;
        #pragma unroll
        for (int i = 0; i < 16; i++) s += part[tid][i];
        gl[tid] = 1.f / (1.f + __expf(-(s + b_g2[0])));
    }
    __syncthreads();
    {
        const int nn = tid >> 4, o = (tid & 15) * 8;
        const float gv = gl[nn];
        const int gbase = (n0 + nn) * 128 + o;
        float4 x0 = *(const float4*)(x + gbase);
        float4 x1 = *(const float4*)(x + gbase + 4);
        float r[8];
        #pragma unroll
        for (int t = 0; t < 4; t++){
            u32 hi = Hsh[nn][(o >> 1) + t];
            u32 ho = Hsh[nn][64 + (o >> 1) + t];
            r[2*t]   = gv * bf_lo(hi) + (1.f - gv) * bf_lo(ho);
            r[2*t+1] = gv * bf_hi(hi) + (1.f - gv) * bf_hi(ho);
        }
        *(float4*)(out + gbase)     = make_float4(r[0]+x0.x, r[1]+x0.y, r[2]+x0.z, r[3]+x0.w);
        *(float4*)(out + gbase + 4) = make_float4(r[4]+x1.x, r[5]+x1.y, r[6]+x1.z, r[7]+x1.w);
    }
}

extern "C" void kernel_launch(void* const* d_in, const int* in_sizes, int n_in,
                              void* d_out, int out_size, void* d_ws, size_t ws_size,
                              hipStream_t stream){
    const float* x     = (const float*)d_in[0];
    const int*   ei    = (const int*)d_in[1];          // int32 (JAX x64 off)
    const float* w_s2d = (const float*)d_in[2];
    const float* b_s2d = (const float*)d_in[3];
    const float* w_d2s = (const float*)d_in[4];
    const float* b_d2s = (const float*)d_in[5];
    const float* w_e1  = (const float*)d_in[6];
    const float* b_e1  = (const float*)d_in[7];
    const float* w_e2  = (const float*)d_in[8];
    const float* b_e2  = (const float*)d_in[9];
    const float* w_g1  = (const float*)d_in[10];
    const float* b_g1  = (const float*)d_in[11];
    const float* w_g2  = (const float*)d_in[12];
    const float* b_g2  = (const float*)d_in[13];
    float* out = (float*)d_out;
    u32*   T1  = (u32*)d_out;                    // fp8 [A|B], first 12.8 MB
    uint2* Bd  = (uint2*)((u32*)d_out + 3200000); // second half: 6.4 MB
    uint2* Bs  = Bd + N_EDGES;                    // + 6.4 MB (= 25.6 MB total)
    u32*   Y   = (u32*)d_out;                    // bf16 [y_in|y_out] (after bucket2)

    char* ws = (char*)d_ws;
    size_t off = 0;
    #define TAKE(name, bytes) char* name = ws + off; off += (((size_t)(bytes)) + 511) & ~(size_t)511;
    TAKE(pk1_b,   32768 * 2)
    TAKE(pkM_b,   32768 * 2)
    TAKE(pkG_b,   32768 * 2)
    TAKE(bias1_b, 256 * 4)
    TAKE(xb_b,    (size_t)N_NODES * 128 * 2)  // x in bf16 (proj), 12.8 MB
    TAKE(xf8_b,   (size_t)N_NODES * 128)      // x in fp8 (gather), 6.4 MB
    TAKE(score_b, (size_t)N_EDGES * 2)
    TAKE(bcnt_b,  (size_t)2 * NBKT * 4)
    TAKE(bbase_b, (size_t)2 * (NBKT + 1) * 4)
    TAKE(bhist_b, (size_t)CNTBLK * 2 * NBKT * 4)  // per-block histograms, 613 KB
    TAKE(rb_b,    (size_t)CNTBLK * 2 * NBKT * 4)  // per-block bases, 613 KB
    TAKE(cnt_b,   (size_t)2 * N_NODES * 4)    // cnt_dst | cnt_src
    TAKE(sd_b,    (size_t)N_NODES * 4)        // start_dst
    TAKE(ss2_b,   (size_t)N_NODES * 4)        // start_src
    TAKE(ipay_b,  (size_t)N_EDGES * 4)
    TAKE(opay_b,  (size_t)N_EDGES * 4)
    TAKE(ssin_b,  (size_t)N_NODES * 4)
    TAKE(ssout_b, (size_t)N_NODES * 4)
    #undef TAKE
    (void)ws_size; (void)in_sizes; (void)n_in; (void)out_size;
    // total ~30 MB

    hipMemsetAsync(bcnt_b, 0, (size_t)2 * NBKT * 4, stream);
    setup_kernel<<<XCBLK + 386 + CNTBLK, 256, 0, stream>>>(x, w_s2d, w_d2s, w_e1, w_g1, b_e1, ei,
        (uint2*)xb_b, (u32*)xf8_b, (u16*)pk1_b, (u16*)pkM_b, (u16*)pkG_b,
        (float*)bias1_b, (u32*)bcnt_b, (u32*)bhist_b);
    proj_mfma_kernel<<<N_NODES / 16, 256, 0, stream>>>((const u16*)xb_b,
        (const u16*)pk1_b, (const float*)bias1_b, T1);
    edge_score_kernel<<<N_EDGES / 32, 256, 0, stream>>>((const u32*)T1, ei, w_e2, b_e2,
        (u16*)score_b);
    bucket_scan_kernel<<<2, 512, 0, stream>>>((const u32*)bcnt_b, (const u32*)bhist_b,
        (u32*)bbase_b, (u32*)rb_b);
    bucket1_kernel<<<CNTBLK, 256, 0, stream>>>(ei, (const u16*)score_b,
        (const u32*)rb_b, Bd, Bs);
    bucket2_kernel<<<2 * NBKT, 256, 0, stream>>>(Bd, Bs, (const u32*)bbase_b,
        (u32*)cnt_b, (u32*)sd_b, (u32*)cnt_b + N_NODES, (u32*)ss2_b,
        (u32*)ipay_b, (u32*)opay_b);
    gather_kernel<<<N_NODES / 2, 256, 0, stream>>>((const u32*)xf8_b,
        (const u32*)ipay_b, (const u32*)opay_b,
        (const u32*)cnt_b, (const u32*)sd_b, (const u32*)cnt_b + N_NODES, (const u32*)ss2_b,
        Y, (float*)ssin_b, (float*)ssout_b);
    finale_mfma_kernel<<<N_NODES / 16, 256, 0, stream>>>((const u32*)Y, x,
        (const u16*)pkM_b, (const u16*)pkG_b, b_s2d, b_d2s,
        (const float*)ssin_b, (const float*)ssout_b,
        (const u32*)cnt_b, (const u32*)cnt_b + N_NODES,
        b_g1, w_g2, b_g2, out);
}